// Round 4
// baseline (1460.627 us; speedup 1.0000x reference)
//
#include <hip/hip_runtime.h>

#define NB 64      // batch
#define SEQ 305    // sequence length
#define DIM 2048   // hidden
#define NP 256     // patches
#define NT 48      // task tokens
#define NKEEP 128  // kept patches
#define SOUT 177   // 1 + 128 + 48
#define NDC 8      // split-K chunks over D
#define DCHUNK 256 // DIM / NDC
#define KS 32      // d-depth per LDS stage (32 floats = 128B per row: full lines)
#define NCHUNK 8   // DCHUNK / KS

static_assert(1 + NP + NT == SEQ, "layout");

constexpr float kScale = 0.022097086912079608f;  // 1/sqrt(2048)

// ---------------------------------------------------------------------------
// K1a: grid (1+NDC, 64). blockIdx.x==0: stream cls+task rows to out (static
// copy, overlaps with GEMM blocks). Else: split-K partial GEMM, tile
// 256p x 48t, micro-tile 8x6, KS=32. LDS [row][32] with XOR-swizzled f4 slot
// (slot = c8 ^ ((row>>3)&7)): b128 writes AND b128 reads, conflict-free.
// ssq fused into compute on predicated lanes (tg==0 rows, pg==0 cols).
// ---------------------------------------------------------------------------
__global__ __launch_bounds__(256, 2) void k1a_partial_gemm(
    const float* __restrict__ tokens, float* __restrict__ rpart,
    float* __restrict__ ssqP, float* __restrict__ ssqT,
    float* __restrict__ out0) {
  const int b = blockIdx.y;
  const int t = threadIdx.x;

  if (blockIdx.x == 0) {
    // copy cls (row 0 -> 0) and task rows (257..304 -> 129..176): 49 rows
#pragma unroll 2
    for (int l = 0; l < 98; ++l) {
      int u = l * 256 + t;  // 49 rows * 512 f4
      int row = u >> 9, c = u & 511;
      int srow = (row == 0) ? 0 : (256 + row);
      int drow = (row == 0) ? 0 : (128 + row);
      *(float4*)(out0 + ((size_t)b * SOUT + drow) * DIM + (size_t)c * 4) =
          *(const float4*)(tokens + ((size_t)b * SEQ + srow) * DIM + (size_t)c * 4);
    }
    return;
  }

  const int dci = blockIdx.x - 1;
  const int pg = t >> 3;  // 0..31: rows pg*8..pg*8+7
  const int tg = t & 7;   // 0..7:  cols tg*6..tg*6+5

  __shared__ __align__(16) float pC[256][32];
  __shared__ __align__(16) float tC[48][32];

  const float* pbase = tokens + ((size_t)b * SEQ + 1) * DIM + dci * DCHUNK;
  const float* tbase = tokens + ((size_t)b * SEQ + 1 + NP) * DIM + dci * DCHUNK;

  float4 st[10];
  float acc[8][6] = {};
  float sqp[8] = {};
  float sqt[6] = {};

  // staging map: u = t + 256*l. u<2048: p f4 (row=u>>3, c8=u&7);
  // 2048<=u<2432: t f4 (v=u-2048: row=v>>3, c8=v&7).
  auto gload = [&](int ck) {
#pragma unroll
    for (int l = 0; l < 10; ++l) {
      int u = t + 256 * l;
      if (u < 2048) {
        int row = u >> 3, c8 = u & 7;
        st[l] = *(const float4*)(pbase + (size_t)row * DIM + ck * KS + c8 * 4);
      } else if (u < 2432) {
        int v = u - 2048;
        int row = v >> 3, c8 = v & 7;
        st[l] = *(const float4*)(tbase + (size_t)row * DIM + ck * KS + c8 * 4);
      }
    }
  };
  auto lwrite = [&]() {
#pragma unroll
    for (int l = 0; l < 10; ++l) {
      int u = t + 256 * l;
      if (u < 2048) {
        int row = u >> 3, c8 = u & 7;
        int sl = c8 ^ ((row >> 3) & 7);
        *(float4*)&pC[row][sl * 4] = st[l];
      } else if (u < 2432) {
        int v = u - 2048;
        int row = v >> 3, c8 = v & 7;
        int sl = c8 ^ ((row >> 3) & 7);
        *(float4*)&tC[row][sl * 4] = st[l];
      }
    }
  };

  gload(0);
  for (int ck = 0; ck < NCHUNK; ++ck) {
    __syncthreads();  // previous compute done reading LDS
    lwrite();
    if (ck + 1 < NCHUNK) gload(ck + 1);  // overlap with compute below
    __syncthreads();  // staged data visible
#pragma unroll
    for (int j0 = 0; j0 < 8; ++j0) {
      float4 pv[8];
#pragma unroll
      for (int i = 0; i < 8; ++i)
        pv[i] = *(const float4*)&pC[pg * 8 + i][(j0 ^ (pg & 7)) * 4];
      float4 tv[6];
#pragma unroll
      for (int j = 0; j < 6; ++j) {
        int trow = tg * 6 + j;
        tv[j] = *(const float4*)&tC[trow][(j0 ^ ((trow >> 3) & 7)) * 4];
      }
#pragma unroll
      for (int i = 0; i < 8; ++i)
#pragma unroll
        for (int j = 0; j < 6; ++j)
          acc[i][j] += pv[i].x * tv[j].x + pv[i].y * tv[j].y +
                       pv[i].z * tv[j].z + pv[i].w * tv[j].w;
      if (tg == 0) {
#pragma unroll
        for (int i = 0; i < 8; ++i)
          sqp[i] += pv[i].x * pv[i].x + pv[i].y * pv[i].y +
                    pv[i].z * pv[i].z + pv[i].w * pv[i].w;
      }
      if (pg == 0) {
#pragma unroll
        for (int j = 0; j < 6; ++j)
          sqt[j] += tv[j].x * tv[j].x + tv[j].y * tv[j].y +
                    tv[j].z * tv[j].z + tv[j].w * tv[j].w;
      }
    }
  }

  // partial R, transposed: rpart[(b*NDC+dci)][jg][256] (coalesced both sides)
  float* rp = rpart + ((size_t)b * NDC + dci) * (NT * NP);
#pragma unroll
  for (int j = 0; j < 6; ++j) {
    int jg = tg * 6 + j;
    float4 v0 = {acc[0][j], acc[1][j], acc[2][j], acc[3][j]};
    float4 v1 = {acc[4][j], acc[5][j], acc[6][j], acc[7][j]};
    *(float4*)(rp + jg * NP + pg * 8) = v0;
    *(float4*)(rp + jg * NP + pg * 8 + 4) = v1;
  }
  if (tg == 0) {
    float* sp = ssqP + ((size_t)b * NDC + dci) * NP + pg * 8;
#pragma unroll
    for (int i = 0; i < 8; ++i) sp[i] = sqp[i];
  }
  if (pg == 0) {
    float* stp = ssqT + ((size_t)b * NDC + dci) * NT + tg * 6;
#pragma unroll
    for (int j = 0; j < 6; ++j) stp[j] = sqt[j];
  }
}

// ---------------------------------------------------------------------------
// K1b: grid (4 pt, 64 b), 256 thr. Sum NDC partials in fixed order
// (deterministic), rms + softmax, write attnp = softmax*invT and
// rn = raw*invP. Inits umax.
// ---------------------------------------------------------------------------
__global__ __launch_bounds__(256) void k1b_reduce_softmax(
    const float* __restrict__ rpart, const float* __restrict__ ssqP,
    const float* __restrict__ ssqT, float* __restrict__ attnp,
    float* __restrict__ rn, unsigned long long* __restrict__ umax) {
  const int pt = blockIdx.x;
  const int b = blockIdx.y;
  const int t = threadIdx.x;
  const int r = t & 63;
  const int q = t >> 6;

  __shared__ float L[64][49];
  __shared__ float invPs[64];
  __shared__ float invTs[48];

  float a[12] = {};
  const float* rb = rpart + (size_t)b * NDC * (NT * NP) + pt * 64 + r;
  for (int dci = 0; dci < NDC; ++dci) {
    const float* rp = rb + (size_t)dci * (NT * NP);
#pragma unroll
    for (int j = 0; j < 12; ++j) a[j] += rp[(q * 12 + j) * NP];
  }
#pragma unroll
  for (int j = 0; j < 12; ++j) L[r][q * 12 + j] = a[j];

  if (t < 64) {
    float s = 0.f;
    for (int dci = 0; dci < NDC; ++dci)
      s += ssqP[((size_t)b * NDC + dci) * NP + pt * 64 + t];
    invPs[t] = 1.0f / sqrtf(s * (1.0f / 2048.0f) + 1e-6f);
    umax[(size_t)b * NP + pt * 64 + t] = 0ull;
  } else if (t < 112) {
    int j = t - 64;
    float s = 0.f;
    for (int dci = 0; dci < NDC; ++dci)
      s += ssqT[((size_t)b * NDC + dci) * NT + j];
    invTs[j] = 1.0f / sqrtf(s * (1.0f / 2048.0f) + 1e-6f);
  }
  __syncthreads();

  if (t < 64) {
    const float invp = invPs[t];
    float lg[48];
    float m = -3.4e38f;
#pragma unroll
    for (int j = 0; j < 48; ++j) {
      lg[j] = L[t][j] * invp * invTs[j] * kScale;
      m = fmaxf(m, lg[j]);
    }
    float s = 0.f;
#pragma unroll
    for (int j = 0; j < 48; ++j) {
      lg[j] = expf(lg[j] - m);
      s += lg[j];
    }
    const float is = 1.0f / s;
    float* ao = attnp + ((size_t)b * NP + pt * 64 + t) * NT;
    float* ro = rn + ((size_t)b * NP + pt * 64 + t) * NT;
#pragma unroll
    for (int j = 0; j < 48; ++j) ao[j] = lg[j] * is * invTs[j];
#pragma unroll
    for (int j = 0; j < 48; ++j) ro[j] = L[t][j] * invp;
  }
}

// ---------------------------------------------------------------------------
// K2: score[p][q] = sum_t attn'[p][t] * Rn[q][t], argmax over q folded in via
// packed (mono-float | ~q) atomicMax (order-independent -> deterministic).
// ---------------------------------------------------------------------------
__global__ __launch_bounds__(256) void k2_score_argmax(
    const float* __restrict__ attnp, const float* __restrict__ rn,
    unsigned long long* __restrict__ umax) {
  const int b = blockIdx.y;
  const int qt = blockIdx.x & 3;
  const int pb = blockIdx.x >> 2;
  const int t = threadIdx.x;
  const int tp = t >> 4, tq = t & 15;

  __shared__ float aS[48][68];
  __shared__ float rS[48][68];

  const float* ab = attnp + ((size_t)b * NP + pb * 64) * NT;
  const float* rb = rn + ((size_t)b * NP + qt * 64) * NT;
#pragma unroll
  for (int l = 0; l < 3; ++l) {
    int u = t + 256 * l;  // 64 rows x 12 f4
    int row = u / 12, c4 = u % 12;
    float4 v = *(const float4*)(ab + (size_t)row * NT + c4 * 4);
    aS[c4 * 4 + 0][row] = v.x;
    aS[c4 * 4 + 1][row] = v.y;
    aS[c4 * 4 + 2][row] = v.z;
    aS[c4 * 4 + 3][row] = v.w;
    float4 w = *(const float4*)(rb + (size_t)row * NT + c4 * 4);
    rS[c4 * 4 + 0][row] = w.x;
    rS[c4 * 4 + 1][row] = w.y;
    rS[c4 * 4 + 2][row] = w.z;
    rS[c4 * 4 + 3][row] = w.w;
  }
  __syncthreads();

  float acc[4][4] = {};
#pragma unroll
  for (int k = 0; k < 48; ++k) {
    float4 av = *(const float4*)&aS[k][tp * 4];
    float4 rv = *(const float4*)&rS[k][tq * 4];
    float aa[4] = {av.x, av.y, av.z, av.w};
    float rr[4] = {rv.x, rv.y, rv.z, rv.w};
#pragma unroll
    for (int i = 0; i < 4; ++i)
#pragma unroll
      for (int j = 0; j < 4; ++j) acc[i][j] += aa[i] * rr[j];
  }

#pragma unroll
  for (int i = 0; i < 4; ++i) {
    float bs = acc[i][0];
    int bq = qt * 64 + tq * 4;
#pragma unroll
    for (int j = 1; j < 4; ++j) {
      float s = acc[i][j];
      int qq = qt * 64 + tq * 4 + j;
      if (s > bs) {  // strict > keeps smallest q on ties
        bs = s;
        bq = qq;
      }
    }
    unsigned us = __float_as_uint(bs);
    us = (us & 0x80000000u) ? ~us : (us | 0x80000000u);
    unsigned long long key =
        ((unsigned long long)us << 32) | (unsigned long long)(0xFFFFFFFFu - (unsigned)bq);
    for (int o = 8; o >= 1; o >>= 1) {
      unsigned long long ok = __shfl_xor(key, o, 16);
      if (ok > key) key = ok;
    }
    if (tq == 0) atomicMax(&umax[(size_t)b * NP + pb * 64 + tp * 4 + i], key);
  }
}

// ---------------------------------------------------------------------------
// K3: per batch: decode argmax, vote counts, exact rank (count desc, idx asc),
// keep rank<128, emit ascending; gather pos/mask in the same block.
// ---------------------------------------------------------------------------
__global__ __launch_bounds__(256) void k3_select_meta(
    const unsigned long long* __restrict__ umax, const int* __restrict__ pos,
    const int* __restrict__ msk, int* __restrict__ order,
    float* __restrict__ out1, float* __restrict__ out2) {
  const int b = blockIdx.x, t = threadIdx.x;
  __shared__ int cnt[256];
  __shared__ int kept[256];
  __shared__ int sorder[NKEEP];
  cnt[t] = 0;
  __syncthreads();
  unsigned long long key = umax[(size_t)b * NP + t];
  int q = (int)(0xFFFFFFFFu - (unsigned)(key & 0xFFFFFFFFull));
  atomicAdd(&cnt[q], 1);
  __syncthreads();
  const int c = cnt[t];
  int rank = 0;
  for (int u = 0; u < 256; ++u) {
    int cu = cnt[u];
    rank += (cu > c || (cu == c && u < t)) ? 1 : 0;
  }
  kept[t] = (rank < NKEEP) ? 1 : 0;
  __syncthreads();
  if (kept[t]) {
    int posn = 0;
    for (int u = 0; u < t; ++u) posn += kept[u];
    order[b * NKEEP + posn] = t;
    sorder[posn] = t;
  }
  __syncthreads();
  if (t < SOUT) {
    int src;
    if (t == 0) src = 0;
    else if (t < 1 + NKEEP) src = 1 + sorder[t - 1];
    else src = t + (NP - NKEEP);
    out1[b * SOUT + t] = (float)pos[b * SEQ + src];
    out2[b * SOUT + t] = (float)msk[b * SEQ + src];
  }
}

// ---------------------------------------------------------------------------
// K4: gather only the 128 kept patch rows (cls/task copied in k1a).
// ---------------------------------------------------------------------------
__global__ __launch_bounds__(256) void k4_gather_kept(
    const float* __restrict__ tokens, const int* __restrict__ order,
    float* __restrict__ out) {
  const int ki = blockIdx.x;  // 0..127
  const int b = blockIdx.y;
  const int t = threadIdx.x;
  const int src = 1 + order[b * NKEEP + ki];
  const float4* in4 = (const float4*)(tokens + ((size_t)b * SEQ + src) * DIM);
  float4* o4 = (float4*)(out + ((size_t)b * SOUT + 1 + ki) * DIM);
  o4[t] = in4[t];
  o4[t + 256] = in4[t + 256];
}

// ---------------------------------------------------------------------------
extern "C" void kernel_launch(void* const* d_in, const int* in_sizes, int n_in,
                              void* d_out, int out_size, void* d_ws,
                              size_t ws_size, hipStream_t stream) {
  const float* tokens = (const float*)d_in[0];
  const int* pos = (const int*)d_in[1];
  const int* msk = (const int*)d_in[2];

  float* out0 = (float*)d_out;
  float* out1 = out0 + (size_t)NB * SOUT * DIM;
  float* out2 = out1 + (size_t)NB * SOUT;

  char* ws = (char*)d_ws;
  float* attnp = (float*)ws;                 // NB*NP*NT
  float* rn = attnp + (size_t)NB * NP * NT;  // NB*NP*NT
  unsigned long long* umax = (unsigned long long*)(rn + (size_t)NB * NP * NT);
  int* order = (int*)(umax + (size_t)NB * NP);
  float* rpart = (float*)(order + (size_t)NB * NKEEP);  // NB*NDC*48*256
  float* ssqP = rpart + (size_t)NB * NDC * NT * NP;     // NB*NDC*256
  float* ssqT = ssqP + (size_t)NB * NDC * NP;           // NB*NDC*48

  k1a_partial_gemm<<<dim3(1 + NDC, NB), 256, 0, stream>>>(tokens, rpart, ssqP,
                                                          ssqT, out0);
  k1b_reduce_softmax<<<dim3(4, NB), 256, 0, stream>>>(rpart, ssqP, ssqT, attnp,
                                                      rn, umax);
  k2_score_argmax<<<dim3(16, NB), 256, 0, stream>>>(attnp, rn, umax);
  k3_select_meta<<<NB, 256, 0, stream>>>(umax, pos, msk, order, out1, out2);
  k4_gather_kept<<<dim3(NKEEP, NB), 256, 0, stream>>>(tokens, order, out0);
}

// Round 5
// 368.943 us; speedup vs baseline: 3.9590x; 3.9590x over previous
//
#include <hip/hip_runtime.h>

#define NB 64      // batch
#define SEQ 305    // sequence length
#define DIM 2048   // hidden
#define NP 256     // patches
#define NT 48      // task tokens
#define NKEEP 128  // kept patches
#define SOUT 177   // 1 + 128 + 48
#define NDC 8      // split-K chunks over D
#define DCHUNK 256 // DIM / NDC
#define KS 32      // d-depth per LDS stage (32 floats = 128B per row)
#define NCHUNK 8   // DCHUNK / KS

static_assert(1 + NP + NT == SEQ, "layout");

constexpr float kScale = 0.022097086912079608f;  // 1/sqrt(2048)

// ---------------------------------------------------------------------------
// K1a: grid (1+NDC, 64). blockIdx.x==0: stream cls+task rows to out (static
// copy, overlaps with GEMM blocks). Else: split-K partial GEMM, tile
// 256p x 48t, micro-tile 8x6, KS=32. Staging via global_load_lds (16B/lane,
// no staging VGPRs -> no spills). LDS layout [row][slot] linear; XOR swizzle
// (col = slot ^ ((row>>3)&7)) applied on the GLOBAL source address, so
// b128 reads at slot = j0 ^ rowbits are conflict-free.
// ---------------------------------------------------------------------------
__global__ __launch_bounds__(256) void k1a_partial_gemm(
    const float* __restrict__ tokens, float* __restrict__ rpart,
    float* __restrict__ ssqP, float* __restrict__ ssqT,
    float* __restrict__ out0) {
  const int b = blockIdx.y;
  const int t = threadIdx.x;

  if (blockIdx.x == 0) {
    // copy cls (row 0 -> 0) and task rows (257..304 -> 129..176)
#pragma unroll 2
    for (int l = 0; l < 98; ++l) {
      int u = l * 256 + t;  // 49 rows * 512 f4
      int row = u >> 9, c = u & 511;
      int srow = (row == 0) ? 0 : (256 + row);
      int drow = (row == 0) ? 0 : (128 + row);
      *(float4*)(out0 + ((size_t)b * SOUT + drow) * DIM + (size_t)c * 4) =
          *(const float4*)(tokens + ((size_t)b * SEQ + srow) * DIM + (size_t)c * 4);
    }
    return;
  }

  const int dci = blockIdx.x - 1;
  const int pg = t >> 3;   // 0..31: rows pg*8..pg*8+7
  const int tg = t & 7;    // 0..7:  cols tg*6..tg*6+5
  const int w = t >> 6;    // wave id 0..3
  const int lane = t & 63;

  __shared__ __align__(16) float pC[256][32];  // 32 KB
  __shared__ __align__(16) float tC[48][32];   // 6 KB

  const float* pbase = tokens + ((size_t)b * SEQ + 1) * DIM + dci * DCHUNK;
  const float* tbase = tokens + ((size_t)b * SEQ + 1 + NP) * DIM + dci * DCHUNK;

  float acc[8][6] = {};
  float sqp[8] = {};
  float sqt[6] = {};

  for (int ck = 0; ck < NCHUNK; ++ck) {
    __syncthreads();  // previous chunk's readers done
    {
      const float* pb = pbase + ck * KS;
      const float* tb = tbase + ck * KS;
      // 38 wave-calls: c<32 -> pC (2048 f4), 32..37 -> tC (384 f4).
      for (int c = w; c < 38; c += 4) {
        int f = c * 64 + lane;
        const float* g;
        float* l;
        if (c < 32) {
          int row = f >> 3, sl = f & 7;
          int col = sl ^ ((row >> 3) & 7);
          g = pb + (size_t)row * DIM + col * 4;
          l = &pC[0][0] + c * 256;  // wave-uniform base; HW adds lane*16
        } else {
          int v = f - 2048;
          int row = v >> 3, sl = v & 7;
          int col = sl ^ ((row >> 3) & 7);
          g = tb + (size_t)row * DIM + col * 4;
          l = &tC[0][0] + (c - 32) * 256;
        }
        __builtin_amdgcn_global_load_lds(
            (const __attribute__((address_space(1))) unsigned int*)g,
            (__attribute__((address_space(3))) unsigned int*)l, 16, 0, 0);
      }
    }
    __syncthreads();  // compiler drains vmcnt(0) before barrier -> data visible

#pragma unroll
    for (int j0 = 0; j0 < 8; ++j0) {
      float4 tv[6];
#pragma unroll
      for (int j = 0; j < 6; ++j) {
        int trow = tg * 6 + j;
        tv[j] = *(const float4*)&tC[trow][((j0 ^ (trow >> 3)) & 7) * 4];
      }
      if (pg == 0) {
#pragma unroll
        for (int j = 0; j < 6; ++j)
          sqt[j] += tv[j].x * tv[j].x + tv[j].y * tv[j].y +
                    tv[j].z * tv[j].z + tv[j].w * tv[j].w;
      }
      const int psl = ((j0 ^ pg) & 7) * 4;
#pragma unroll
      for (int i = 0; i < 8; ++i) {
        float4 pv = *(const float4*)&pC[pg * 8 + i][psl];
#pragma unroll
        for (int j = 0; j < 6; ++j)
          acc[i][j] += pv.x * tv[j].x + pv.y * tv[j].y + pv.z * tv[j].z +
                       pv.w * tv[j].w;
        if (tg == 0)
          sqp[i] += pv.x * pv.x + pv.y * pv.y + pv.z * pv.z + pv.w * pv.w;
      }
    }
  }

  // partial R, transposed: rpart[(b*NDC+dci)][jg][256] (coalesced both sides)
  float* rp = rpart + ((size_t)b * NDC + dci) * (NT * NP);
#pragma unroll
  for (int j = 0; j < 6; ++j) {
    int jg = tg * 6 + j;
    float4 v0 = {acc[0][j], acc[1][j], acc[2][j], acc[3][j]};
    float4 v1 = {acc[4][j], acc[5][j], acc[6][j], acc[7][j]};
    *(float4*)(rp + jg * NP + pg * 8) = v0;
    *(float4*)(rp + jg * NP + pg * 8 + 4) = v1;
  }
  if (tg == 0) {
    float* sp = ssqP + ((size_t)b * NDC + dci) * NP + pg * 8;
#pragma unroll
    for (int i = 0; i < 8; ++i) sp[i] = sqp[i];
  }
  if (pg == 0) {
    float* stp = ssqT + ((size_t)b * NDC + dci) * NT + tg * 6;
#pragma unroll
    for (int j = 0; j < 6; ++j) stp[j] = sqt[j];
  }
}

// ---------------------------------------------------------------------------
// K1b: grid (4 pt, 64 b), 256 thr. Sum NDC partials in fixed order
// (deterministic), rms + softmax, write attnp = softmax*invT and
// rn = raw*invP. Inits umax.
// ---------------------------------------------------------------------------
__global__ __launch_bounds__(256) void k1b_reduce_softmax(
    const float* __restrict__ rpart, const float* __restrict__ ssqP,
    const float* __restrict__ ssqT, float* __restrict__ attnp,
    float* __restrict__ rn, unsigned long long* __restrict__ umax) {
  const int pt = blockIdx.x;
  const int b = blockIdx.y;
  const int t = threadIdx.x;
  const int r = t & 63;
  const int q = t >> 6;

  __shared__ float L[64][49];
  __shared__ float invPs[64];
  __shared__ float invTs[48];

  float a[12] = {};
  const float* rb = rpart + (size_t)b * NDC * (NT * NP) + pt * 64 + r;
  for (int dci = 0; dci < NDC; ++dci) {
    const float* rp = rb + (size_t)dci * (NT * NP);
#pragma unroll
    for (int j = 0; j < 12; ++j) a[j] += rp[(q * 12 + j) * NP];
  }
#pragma unroll
  for (int j = 0; j < 12; ++j) L[r][q * 12 + j] = a[j];

  if (t < 64) {
    float s = 0.f;
    for (int dci = 0; dci < NDC; ++dci)
      s += ssqP[((size_t)b * NDC + dci) * NP + pt * 64 + t];
    invPs[t] = 1.0f / sqrtf(s * (1.0f / 2048.0f) + 1e-6f);
    umax[(size_t)b * NP + pt * 64 + t] = 0ull;
  } else if (t < 112) {
    int j = t - 64;
    float s = 0.f;
    for (int dci = 0; dci < NDC; ++dci)
      s += ssqT[((size_t)b * NDC + dci) * NT + j];
    invTs[j] = 1.0f / sqrtf(s * (1.0f / 2048.0f) + 1e-6f);
  }
  __syncthreads();

  if (t < 64) {
    const float invp = invPs[t];
    float lg[48];
    float m = -3.4e38f;
#pragma unroll
    for (int j = 0; j < 48; ++j) {
      lg[j] = L[t][j] * invp * invTs[j] * kScale;
      m = fmaxf(m, lg[j]);
    }
    float s = 0.f;
#pragma unroll
    for (int j = 0; j < 48; ++j) {
      lg[j] = expf(lg[j] - m);
      s += lg[j];
    }
    const float is = 1.0f / s;
    float* ao = attnp + ((size_t)b * NP + pt * 64 + t) * NT;
    float* ro = rn + ((size_t)b * NP + pt * 64 + t) * NT;
#pragma unroll
    for (int j = 0; j < 48; ++j) ao[j] = lg[j] * is * invTs[j];
#pragma unroll
    for (int j = 0; j < 48; ++j) ro[j] = L[t][j] * invp;
  }
}

// ---------------------------------------------------------------------------
// K2: score[p][q] = sum_t attn'[p][t] * Rn[q][t], argmax over q folded in via
// packed (mono-float | ~q) atomicMax (order-independent -> deterministic).
// ---------------------------------------------------------------------------
__global__ __launch_bounds__(256) void k2_score_argmax(
    const float* __restrict__ attnp, const float* __restrict__ rn,
    unsigned long long* __restrict__ umax) {
  const int b = blockIdx.y;
  const int qt = blockIdx.x & 3;
  const int pb = blockIdx.x >> 2;
  const int t = threadIdx.x;
  const int tp = t >> 4, tq = t & 15;

  __shared__ float aS[48][68];
  __shared__ float rS[48][68];

  const float* ab = attnp + ((size_t)b * NP + pb * 64) * NT;
  const float* rb = rn + ((size_t)b * NP + qt * 64) * NT;
#pragma unroll
  for (int l = 0; l < 3; ++l) {
    int u = t + 256 * l;  // 64 rows x 12 f4
    int row = u / 12, c4 = u % 12;
    float4 v = *(const float4*)(ab + (size_t)row * NT + c4 * 4);
    aS[c4 * 4 + 0][row] = v.x;
    aS[c4 * 4 + 1][row] = v.y;
    aS[c4 * 4 + 2][row] = v.z;
    aS[c4 * 4 + 3][row] = v.w;
    float4 wv = *(const float4*)(rb + (size_t)row * NT + c4 * 4);
    rS[c4 * 4 + 0][row] = wv.x;
    rS[c4 * 4 + 1][row] = wv.y;
    rS[c4 * 4 + 2][row] = wv.z;
    rS[c4 * 4 + 3][row] = wv.w;
  }
  __syncthreads();

  float acc[4][4] = {};
#pragma unroll
  for (int k = 0; k < 48; ++k) {
    float4 av = *(const float4*)&aS[k][tp * 4];
    float4 rv = *(const float4*)&rS[k][tq * 4];
    float aa[4] = {av.x, av.y, av.z, av.w};
    float rr[4] = {rv.x, rv.y, rv.z, rv.w};
#pragma unroll
    for (int i = 0; i < 4; ++i)
#pragma unroll
      for (int j = 0; j < 4; ++j) acc[i][j] += aa[i] * rr[j];
  }

#pragma unroll
  for (int i = 0; i < 4; ++i) {
    float bs = acc[i][0];
    int bq = qt * 64 + tq * 4;
#pragma unroll
    for (int j = 1; j < 4; ++j) {
      float s = acc[i][j];
      int qq = qt * 64 + tq * 4 + j;
      if (s > bs) {  // strict > keeps smallest q on ties
        bs = s;
        bq = qq;
      }
    }
    unsigned us = __float_as_uint(bs);
    us = (us & 0x80000000u) ? ~us : (us | 0x80000000u);
    unsigned long long key =
        ((unsigned long long)us << 32) | (unsigned long long)(0xFFFFFFFFu - (unsigned)bq);
    for (int o = 8; o >= 1; o >>= 1) {
      unsigned long long ok = __shfl_xor(key, o, 16);
      if (ok > key) key = ok;
    }
    if (tq == 0) atomicMax(&umax[(size_t)b * NP + pb * 64 + tp * 4 + i], key);
  }
}

// ---------------------------------------------------------------------------
// K3: per batch: decode argmax, vote counts, exact rank (count desc, idx asc),
// keep rank<128, emit ascending; gather pos/mask in the same block.
// ---------------------------------------------------------------------------
__global__ __launch_bounds__(256) void k3_select_meta(
    const unsigned long long* __restrict__ umax, const int* __restrict__ pos,
    const int* __restrict__ msk, int* __restrict__ order,
    float* __restrict__ out1, float* __restrict__ out2) {
  const int b = blockIdx.x, t = threadIdx.x;
  __shared__ int cnt[256];
  __shared__ int kept[256];
  __shared__ int sorder[NKEEP];
  cnt[t] = 0;
  __syncthreads();
  unsigned long long key = umax[(size_t)b * NP + t];
  int q = (int)(0xFFFFFFFFu - (unsigned)(key & 0xFFFFFFFFull));
  atomicAdd(&cnt[q], 1);
  __syncthreads();
  const int c = cnt[t];
  int rank = 0;
  for (int u = 0; u < 256; ++u) {
    int cu = cnt[u];
    rank += (cu > c || (cu == c && u < t)) ? 1 : 0;
  }
  kept[t] = (rank < NKEEP) ? 1 : 0;
  __syncthreads();
  if (kept[t]) {
    int posn = 0;
    for (int u = 0; u < t; ++u) posn += kept[u];
    order[b * NKEEP + posn] = t;
    sorder[posn] = t;
  }
  __syncthreads();
  if (t < SOUT) {
    int src;
    if (t == 0) src = 0;
    else if (t < 1 + NKEEP) src = 1 + sorder[t - 1];
    else src = t + (NP - NKEEP);
    out1[b * SOUT + t] = (float)pos[b * SEQ + src];
    out2[b * SOUT + t] = (float)msk[b * SEQ + src];
  }
}

// ---------------------------------------------------------------------------
// K4: gather only the 128 kept patch rows (cls/task copied in k1a).
// ---------------------------------------------------------------------------
__global__ __launch_bounds__(256) void k4_gather_kept(
    const float* __restrict__ tokens, const int* __restrict__ order,
    float* __restrict__ out) {
  const int ki = blockIdx.x;  // 0..127
  const int b = blockIdx.y;
  const int t = threadIdx.x;
  const int src = 1 + order[b * NKEEP + ki];
  const float4* in4 = (const float4*)(tokens + ((size_t)b * SEQ + src) * DIM);
  float4* o4 = (float4*)(out + ((size_t)b * SOUT + 1 + ki) * DIM);
  o4[t] = in4[t];
  o4[t + 256] = in4[t + 256];
}

// ---------------------------------------------------------------------------
extern "C" void kernel_launch(void* const* d_in, const int* in_sizes, int n_in,
                              void* d_out, int out_size, void* d_ws,
                              size_t ws_size, hipStream_t stream) {
  const float* tokens = (const float*)d_in[0];
  const int* pos = (const int*)d_in[1];
  const int* msk = (const int*)d_in[2];

  float* out0 = (float*)d_out;
  float* out1 = out0 + (size_t)NB * SOUT * DIM;
  float* out2 = out1 + (size_t)NB * SOUT;

  char* ws = (char*)d_ws;
  float* attnp = (float*)ws;                 // NB*NP*NT
  float* rn = attnp + (size_t)NB * NP * NT;  // NB*NP*NT
  unsigned long long* umax = (unsigned long long*)(rn + (size_t)NB * NP * NT);
  int* order = (int*)(umax + (size_t)NB * NP);
  float* rpart = (float*)(order + (size_t)NB * NKEEP);  // NB*NDC*48*256
  float* ssqP = rpart + (size_t)NB * NDC * NT * NP;     // NB*NDC*256
  float* ssqT = ssqP + (size_t)NB * NDC * NP;           // NB*NDC*48

  k1a_partial_gemm<<<dim3(1 + NDC, NB), 256, 0, stream>>>(tokens, rpart, ssqP,
                                                          ssqT, out0);
  k1b_reduce_softmax<<<dim3(4, NB), 256, 0, stream>>>(rpart, ssqP, ssqT, attnp,
                                                      rn, umax);
  k2_score_argmax<<<dim3(16, NB), 256, 0, stream>>>(attnp, rn, umax);
  k3_select_meta<<<NB, 256, 0, stream>>>(umax, pos, msk, order, out1, out2);
  k4_gather_kept<<<dim3(NKEEP, NB), 256, 0, stream>>>(tokens, order, out0);
}

// Round 6
// 187.779 us; speedup vs baseline: 7.7785x; 1.9648x over previous
//
#include <hip/hip_runtime.h>

#define NB 64      // batch
#define SEQ 305    // sequence length
#define DIM 2048   // hidden
#define NP 256     // patches
#define NT 48      // task tokens
#define NKEEP 128  // kept patches
#define SOUT 177   // 1 + 128 + 48
#define NDC 8      // split-K chunks over D
#define DCHUNK 256 // DIM / NDC
#define KS 32      // d-depth per LDS stage
#define NCHUNK 8   // DCHUNK / KS

static_assert(1 + NP + NT == SEQ, "layout");

constexpr float kScale = 0.022097086912079608f;  // 1/sqrt(2048)

// ---------------------------------------------------------------------------
// K1a: R1-proven skeleton (register-staged prefetch, [d][row] LDS,
// transpose-on-write), micro-tile 8x6 over a 256p x 48t tile.
// grid (1+NDC, 64): x==0 streams cls+task rows to out (fused static copy).
// Per dd per wave LDS: 2x b128 (p rows, 2-way-free) + b128+b64 (t slots,
// 8-padded) for 48 FMA/thread. ssq fused into staging, shfl-reduced.
// ---------------------------------------------------------------------------
__global__ __launch_bounds__(256) void k1a_partial_gemm(
    const float* __restrict__ tokens, float* __restrict__ rpart,
    float* __restrict__ ssqP, float* __restrict__ ssqT,
    float* __restrict__ out0) {
  const int b = blockIdx.y;
  const int t = threadIdx.x;

  if (blockIdx.x == 0) {
    // copy cls (row 0 -> 0) and task rows (257..304 -> 129..176)
#pragma unroll 2
    for (int l = 0; l < 98; ++l) {
      int u = l * 256 + t;  // 49 rows * 512 f4
      int row = u >> 9, c = u & 511;
      int srow = (row == 0) ? 0 : (256 + row);
      int drow = (row == 0) ? 0 : (128 + row);
      *(float4*)(out0 + ((size_t)b * SOUT + drow) * DIM + (size_t)c * 4) =
          *(const float4*)(tokens + ((size_t)b * SEQ + srow) * DIM + (size_t)c * 4);
    }
    return;
  }

  const int dci = blockIdx.x - 1;  // 0..7
  const int pg = t >> 3;           // 0..31: p-rows pg*8..pg*8+7
  const int tg = t & 7;            // 0..7:  t-cols tg*6..tg*6+5

  __shared__ __align__(16) float pC[KS][260];  // [d][p-row], stride 260
  __shared__ __align__(16) float tC[KS][64];   // [d][t-slot]: row r at (r/6)*8+r%6

  const float* pbase = tokens + ((size_t)b * SEQ + 1) * DIM + dci * DCHUNK;
  const float* tbase = tokens + ((size_t)b * SEQ + 1 + NP) * DIM + dci * DCHUNK;

  float4 st[10];
  float acc[8][6] = {};
  float ssqa[10] = {};

  // staging map: u = t + 256*l. u<2048: p f4 (row=u>>3, c8=u&7);
  // 2048<=u<2432: t f4 (v=u-2048: row=v>>3, c8=v&7). l=0..7 pure-p,
  // l=8 pure-t, l=9 t for t<128 (compile-time resolvable per l).
  auto gload = [&](int ck) {
#pragma unroll
    for (int l = 0; l < 10; ++l) {
      int u = t + 256 * l;
      if (u < 2048) {
        int row = u >> 3, c8 = u & 7;
        st[l] = *(const float4*)(pbase + (size_t)row * DIM + ck * KS + c8 * 4);
      } else if (u < 2432) {
        int v = u - 2048;
        int row = v >> 3, c8 = v & 7;
        st[l] = *(const float4*)(tbase + (size_t)row * DIM + ck * KS + c8 * 4);
      }
    }
  };
  auto lwrite = [&]() {
#pragma unroll
    for (int l = 0; l < 10; ++l) {
      int u = t + 256 * l;
      float4 v = st[l];
      if (u < 2048) {
        int row = u >> 3, c8 = u & 7;
        pC[c8 * 4 + 0][row] = v.x;
        pC[c8 * 4 + 1][row] = v.y;
        pC[c8 * 4 + 2][row] = v.z;
        pC[c8 * 4 + 3][row] = v.w;
        ssqa[l] += v.x * v.x + v.y * v.y + v.z * v.z + v.w * v.w;
      } else if (u < 2432) {
        int vv = u - 2048;
        int row = vv >> 3, c8 = vv & 7;
        int slot = (row / 6) * 8 + (row % 6);
        tC[c8 * 4 + 0][slot] = v.x;
        tC[c8 * 4 + 1][slot] = v.y;
        tC[c8 * 4 + 2][slot] = v.z;
        tC[c8 * 4 + 3][slot] = v.w;
        ssqa[l] += v.x * v.x + v.y * v.y + v.z * v.z + v.w * v.w;
      }
    }
  };

  gload(0);
  for (int ck = 0; ck < NCHUNK; ++ck) {
    __syncthreads();  // previous compute done reading LDS
    lwrite();
    if (ck + 1 < NCHUNK) gload(ck + 1);  // prefetch overlaps compute below
    __syncthreads();
#pragma unroll 4
    for (int dd = 0; dd < KS; ++dd) {
      float4 p0 = *(const float4*)&pC[dd][pg * 8];
      float4 p1 = *(const float4*)&pC[dd][pg * 8 + 4];
      float4 t0 = *(const float4*)&tC[dd][tg * 8];
      float2 t1 = *(const float2*)&tC[dd][tg * 8 + 4];
      float pa[8] = {p0.x, p0.y, p0.z, p0.w, p1.x, p1.y, p1.z, p1.w};
      float tb[6] = {t0.x, t0.y, t0.z, t0.w, t1.x, t1.y};
#pragma unroll
      for (int i = 0; i < 8; ++i)
#pragma unroll
        for (int j = 0; j < 6; ++j) acc[i][j] += pa[i] * tb[j];
    }
  }

  // partial R, transposed: rpart[(b*NDC+dci)][jg][256]
  float* rp = rpart + ((size_t)b * NDC + dci) * (NT * NP);
#pragma unroll
  for (int j = 0; j < 6; ++j) {
    int jg = tg * 6 + j;
    float4 v0 = {acc[0][j], acc[1][j], acc[2][j], acc[3][j]};
    float4 v1 = {acc[4][j], acc[5][j], acc[6][j], acc[7][j]};
    *(float4*)(rp + jg * NP + pg * 8) = v0;
    *(float4*)(rp + jg * NP + pg * 8 + 4) = v1;
  }

  // ssq: reduce across the 8 staging lanes of each row (fixed order)
#pragma unroll
  for (int l = 0; l < 10; ++l) {
    float s = ssqa[l];
    s += __shfl_down(s, 4, 8);
    s += __shfl_down(s, 2, 8);
    s += __shfl_down(s, 1, 8);
    ssqa[l] = s;
  }
  if ((t & 7) == 0) {
#pragma unroll
    for (int l = 0; l < 10; ++l) {
      int u = t + 256 * l;
      if (u < 2048) {
        ssqP[((size_t)b * NDC + dci) * NP + (u >> 3)] = ssqa[l];
      } else if (u < 2432) {
        ssqT[((size_t)b * NDC + dci) * NT + ((u - 2048) >> 3)] = ssqa[l];
      }
    }
  }
}

// ---------------------------------------------------------------------------
// K1b: grid (4 pt, 64 b), 256 thr. Sum NDC partials in fixed order
// (deterministic), rms + softmax, write attnp = softmax*invT and
// rn = raw*invP. Inits umax.
// ---------------------------------------------------------------------------
__global__ __launch_bounds__(256) void k1b_reduce_softmax(
    const float* __restrict__ rpart, const float* __restrict__ ssqP,
    const float* __restrict__ ssqT, float* __restrict__ attnp,
    float* __restrict__ rn, unsigned long long* __restrict__ umax) {
  const int pt = blockIdx.x;
  const int b = blockIdx.y;
  const int t = threadIdx.x;
  const int r = t & 63;
  const int q = t >> 6;

  __shared__ float L[64][49];
  __shared__ float invPs[64];
  __shared__ float invTs[48];

  float a[12] = {};
  const float* rb = rpart + (size_t)b * NDC * (NT * NP) + pt * 64 + r;
  for (int dci = 0; dci < NDC; ++dci) {
    const float* rp = rb + (size_t)dci * (NT * NP);
#pragma unroll
    for (int j = 0; j < 12; ++j) a[j] += rp[(q * 12 + j) * NP];
  }
#pragma unroll
  for (int j = 0; j < 12; ++j) L[r][q * 12 + j] = a[j];

  if (t < 64) {
    float s = 0.f;
    for (int dci = 0; dci < NDC; ++dci)
      s += ssqP[((size_t)b * NDC + dci) * NP + pt * 64 + t];
    invPs[t] = 1.0f / sqrtf(s * (1.0f / 2048.0f) + 1e-6f);
    umax[(size_t)b * NP + pt * 64 + t] = 0ull;
  } else if (t < 112) {
    int j = t - 64;
    float s = 0.f;
    for (int dci = 0; dci < NDC; ++dci)
      s += ssqT[((size_t)b * NDC + dci) * NT + j];
    invTs[j] = 1.0f / sqrtf(s * (1.0f / 2048.0f) + 1e-6f);
  }
  __syncthreads();

  if (t < 64) {
    const float invp = invPs[t];
    float lg[48];
    float m = -3.4e38f;
#pragma unroll
    for (int j = 0; j < 48; ++j) {
      lg[j] = L[t][j] * invp * invTs[j] * kScale;
      m = fmaxf(m, lg[j]);
    }
    float s = 0.f;
#pragma unroll
    for (int j = 0; j < 48; ++j) {
      lg[j] = expf(lg[j] - m);
      s += lg[j];
    }
    const float is = 1.0f / s;
    float* ao = attnp + ((size_t)b * NP + pt * 64 + t) * NT;
    float* ro = rn + ((size_t)b * NP + pt * 64 + t) * NT;
#pragma unroll
    for (int j = 0; j < 48; ++j) ao[j] = lg[j] * is * invTs[j];
#pragma unroll
    for (int j = 0; j < 48; ++j) ro[j] = L[t][j] * invp;
  }
}

// ---------------------------------------------------------------------------
// K2: score[p][q] = sum_t attn'[p][t] * Rn[q][t], argmax over q folded in via
// packed (mono-float | ~q) atomicMax (order-independent -> deterministic).
// ---------------------------------------------------------------------------
__global__ __launch_bounds__(256) void k2_score_argmax(
    const float* __restrict__ attnp, const float* __restrict__ rn,
    unsigned long long* __restrict__ umax) {
  const int b = blockIdx.y;
  const int qt = blockIdx.x & 3;
  const int pb = blockIdx.x >> 2;
  const int t = threadIdx.x;
  const int tp = t >> 4, tq = t & 15;

  __shared__ float aS[48][68];
  __shared__ float rS[48][68];

  const float* ab = attnp + ((size_t)b * NP + pb * 64) * NT;
  const float* rb = rn + ((size_t)b * NP + qt * 64) * NT;
#pragma unroll
  for (int l = 0; l < 3; ++l) {
    int u = t + 256 * l;  // 64 rows x 12 f4
    int row = u / 12, c4 = u % 12;
    float4 v = *(const float4*)(ab + (size_t)row * NT + c4 * 4);
    aS[c4 * 4 + 0][row] = v.x;
    aS[c4 * 4 + 1][row] = v.y;
    aS[c4 * 4 + 2][row] = v.z;
    aS[c4 * 4 + 3][row] = v.w;
    float4 wv = *(const float4*)(rb + (size_t)row * NT + c4 * 4);
    rS[c4 * 4 + 0][row] = wv.x;
    rS[c4 * 4 + 1][row] = wv.y;
    rS[c4 * 4 + 2][row] = wv.z;
    rS[c4 * 4 + 3][row] = wv.w;
  }
  __syncthreads();

  float acc[4][4] = {};
#pragma unroll
  for (int k = 0; k < 48; ++k) {
    float4 av = *(const float4*)&aS[k][tp * 4];
    float4 rv = *(const float4*)&rS[k][tq * 4];
    float aa[4] = {av.x, av.y, av.z, av.w};
    float rr[4] = {rv.x, rv.y, rv.z, rv.w};
#pragma unroll
    for (int i = 0; i < 4; ++i)
#pragma unroll
      for (int j = 0; j < 4; ++j) acc[i][j] += aa[i] * rr[j];
  }

#pragma unroll
  for (int i = 0; i < 4; ++i) {
    float bs = acc[i][0];
    int bq = qt * 64 + tq * 4;
#pragma unroll
    for (int j = 1; j < 4; ++j) {
      float s = acc[i][j];
      int qq = qt * 64 + tq * 4 + j;
      if (s > bs) {  // strict > keeps smallest q on ties
        bs = s;
        bq = qq;
      }
    }
    unsigned us = __float_as_uint(bs);
    us = (us & 0x80000000u) ? ~us : (us | 0x80000000u);
    unsigned long long key =
        ((unsigned long long)us << 32) | (unsigned long long)(0xFFFFFFFFu - (unsigned)bq);
    for (int o = 8; o >= 1; o >>= 1) {
      unsigned long long ok = __shfl_xor(key, o, 16);
      if (ok > key) key = ok;
    }
    if (tq == 0) atomicMax(&umax[(size_t)b * NP + pb * 64 + tp * 4 + i], key);
  }
}

// ---------------------------------------------------------------------------
// K3: per batch: decode argmax, vote counts, exact rank (count desc, idx asc),
// keep rank<128, emit ascending; gather pos/mask in the same block.
// ---------------------------------------------------------------------------
__global__ __launch_bounds__(256) void k3_select_meta(
    const unsigned long long* __restrict__ umax, const int* __restrict__ pos,
    const int* __restrict__ msk, int* __restrict__ order,
    float* __restrict__ out1, float* __restrict__ out2) {
  const int b = blockIdx.x, t = threadIdx.x;
  __shared__ int cnt[256];
  __shared__ int kept[256];
  __shared__ int sorder[NKEEP];
  cnt[t] = 0;
  __syncthreads();
  unsigned long long key = umax[(size_t)b * NP + t];
  int q = (int)(0xFFFFFFFFu - (unsigned)(key & 0xFFFFFFFFull));
  atomicAdd(&cnt[q], 1);
  __syncthreads();
  const int c = cnt[t];
  int rank = 0;
  for (int u = 0; u < 256; ++u) {
    int cu = cnt[u];
    rank += (cu > c || (cu == c && u < t)) ? 1 : 0;
  }
  kept[t] = (rank < NKEEP) ? 1 : 0;
  __syncthreads();
  if (kept[t]) {
    int posn = 0;
    for (int u = 0; u < t; ++u) posn += kept[u];
    order[b * NKEEP + posn] = t;
    sorder[posn] = t;
  }
  __syncthreads();
  if (t < SOUT) {
    int src;
    if (t == 0) src = 0;
    else if (t < 1 + NKEEP) src = 1 + sorder[t - 1];
    else src = t + (NP - NKEEP);
    out1[b * SOUT + t] = (float)pos[b * SEQ + src];
    out2[b * SOUT + t] = (float)msk[b * SEQ + src];
  }
}

// ---------------------------------------------------------------------------
// K4: gather only the 128 kept patch rows (cls/task copied in k1a).
// ---------------------------------------------------------------------------
__global__ __launch_bounds__(256) void k4_gather_kept(
    const float* __restrict__ tokens, const int* __restrict__ order,
    float* __restrict__ out) {
  const int ki = blockIdx.x;  // 0..127
  const int b = blockIdx.y;
  const int t = threadIdx.x;
  const int src = 1 + order[b * NKEEP + ki];
  const float4* in4 = (const float4*)(tokens + ((size_t)b * SEQ + src) * DIM);
  float4* o4 = (float4*)(out + ((size_t)b * SOUT + 1 + ki) * DIM);
  o4[t] = in4[t];
  o4[t + 256] = in4[t + 256];
}

// ---------------------------------------------------------------------------
extern "C" void kernel_launch(void* const* d_in, const int* in_sizes, int n_in,
                              void* d_out, int out_size, void* d_ws,
                              size_t ws_size, hipStream_t stream) {
  const float* tokens = (const float*)d_in[0];
  const int* pos = (const int*)d_in[1];
  const int* msk = (const int*)d_in[2];

  float* out0 = (float*)d_out;
  float* out1 = out0 + (size_t)NB * SOUT * DIM;
  float* out2 = out1 + (size_t)NB * SOUT;

  char* ws = (char*)d_ws;
  float* attnp = (float*)ws;                 // NB*NP*NT
  float* rn = attnp + (size_t)NB * NP * NT;  // NB*NP*NT
  unsigned long long* umax = (unsigned long long*)(rn + (size_t)NB * NP * NT);
  int* order = (int*)(umax + (size_t)NB * NP);
  float* rpart = (float*)(order + (size_t)NB * NKEEP);  // NB*NDC*48*256
  float* ssqP = rpart + (size_t)NB * NDC * NT * NP;     // NB*NDC*256
  float* ssqT = ssqP + (size_t)NB * NDC * NP;           // NB*NDC*48

  k1a_partial_gemm<<<dim3(1 + NDC, NB), 256, 0, stream>>>(tokens, rpart, ssqP,
                                                          ssqT, out0);
  k1b_reduce_softmax<<<dim3(4, NB), 256, 0, stream>>>(rpart, ssqP, ssqT, attnp,
                                                      rn, umax);
  k2_score_argmax<<<dim3(16, NB), 256, 0, stream>>>(attnp, rn, umax);
  k3_select_meta<<<NB, 256, 0, stream>>>(umax, pos, msk, order, out1, out2);
  k4_gather_kept<<<dim3(NKEEP, NB), 256, 0, stream>>>(tokens, order, out0);
}